// Round 1
// baseline (387.708 us; speedup 1.0000x reference)
//
#include <hip/hip_runtime.h>

#define N_NODE   4096
#define PLANE    (N_NODE * N_NODE)   // 16777216 floats per Chebyshev plane
#define TAU_MAX  10.0f
#define INV_SCALE 0.01f              // 1/(T1-T0)

// Stable Softplus(beta=100): log(1+exp(100 z))/100 = (max(100z,0)+log1p(exp(-|100z|)))/100
__device__ __forceinline__ float sp100(float z) {
    float a = 100.0f * z;
    float e = __expf(-fabsf(a));
    return (fmaxf(a, 0.0f) + __logf(1.0f + e)) * 0.01f;
}

// One basis-n MLP: 1 -> 5 -> 5 -> 1, softplus100 activations on the two hidden layers.
// All weight indices are wave-uniform -> scalar loads (s_load) + SGPR operands in v_fma.
__device__ __forceinline__ float mlp_n(float t,
                                       const float* __restrict__ W1,
                                       const float* __restrict__ b1,
                                       const float* __restrict__ W2,
                                       const float* __restrict__ b2,
                                       const float* __restrict__ W3,
                                       const float* __restrict__ b3,
                                       int n) {
    float h1[5];
#pragma unroll
    for (int w = 0; w < 5; ++w)
        h1[w] = sp100(fmaf(t, W1[n * 5 + w], b1[n * 5 + w]));

    float h2[5];
#pragma unroll
    for (int v = 0; v < 5; ++v) {
        float acc = b2[n * 5 + v];
#pragma unroll
        for (int w = 0; w < 5; ++w)
            acc = fmaf(h1[w], W2[n * 25 + w * 5 + v], acc);
        h2[v] = sp100(acc);
    }

    float o = b3[n];
#pragma unroll
    for (int w = 0; w < 5; ++w)
        o = fmaf(h2[w], W3[n * 5 + w], o);
    return o;
}

__global__ __launch_bounds__(256)
void tdb_cheb_kernel(const float2* __restrict__ x,   // [B,2] (t, node_idx)
                     const float2* __restrict__ y,   // [B,2]
                     const float*  __restrict__ Bm,  // [4, 4096, 4096]
                     const float*  __restrict__ Wx1, const float* __restrict__ Wx2,
                     const float*  __restrict__ Wx3,
                     const float*  __restrict__ Wy1, const float* __restrict__ Wy2,
                     const float*  __restrict__ Wy3,
                     const float*  __restrict__ bx1, const float* __restrict__ bx2,
                     const float*  __restrict__ bx3,
                     const float*  __restrict__ by1, const float* __restrict__ by2,
                     const float*  __restrict__ by3,
                     const float*  __restrict__ W,   // [4,4]
                     float* __restrict__ out, int batch) {
    int b = blockIdx.x * blockDim.x + threadIdx.x;
    if (b >= batch) return;

    float2 xv = x[b];
    float2 yv = y[b];
    float dt = xv.x - yv.x;

    float res = 0.0f;
    if (dt <= TAU_MAX) {   // masked lanes: out = 0, and their gathers are exec-masked away
        float tx = dt * INV_SCALE;
        float ty = yv.x * INV_SCALE;   // (t_y - T0)/scale, T0 = 0

        int xi = (int)xv.y;
        int yi = (int)yv.y;
        int idx = yi * N_NODE + xi;

        // Issue the 4 random gathers early; ~600 VALU cycles of MLP below hide the miss latency.
        float kl0 = Bm[idx];
        float kl1 = Bm[idx + PLANE];
        float kl2 = Bm[idx + 2 * PLANE];
        float kl3 = Bm[idx + 3 * PLANE];

        float kt[4];
        for (int n = 0; n < 4; ++n) {
            float xb = mlp_n(tx, Wx1, bx1, Wx2, bx2, Wx3, bx3, n);
            float yb = mlp_n(ty, Wy1, by1, Wy2, by2, Wy3, by3, n);
            kt[n] = xb * yb;
        }

        // out = sum_j (sum_i kt[i] * W[i][j]) * kl[j]
        float s0 = 0.f, s1 = 0.f, s2 = 0.f, s3 = 0.f;
#pragma unroll
        for (int i = 0; i < 4; ++i) {
            float k = kt[i];
            s0 = fmaf(k, W[i * 4 + 0], s0);
            s1 = fmaf(k, W[i * 4 + 1], s1);
            s2 = fmaf(k, W[i * 4 + 2], s2);
            s3 = fmaf(k, W[i * 4 + 3], s3);
        }
        res = fmaf(s0, kl0, fmaf(s1, kl1, fmaf(s2, kl2, s3 * kl3)));
    }
    out[b] = res;
}

extern "C" void kernel_launch(void* const* d_in, const int* in_sizes, int n_in,
                              void* d_out, int out_size, void* d_ws, size_t ws_size,
                              hipStream_t stream) {
    const float2* x   = (const float2*)d_in[0];
    const float2* y   = (const float2*)d_in[1];
    const float*  Bm  = (const float*)d_in[2];
    const float*  Wx1 = (const float*)d_in[3];
    const float*  Wx2 = (const float*)d_in[4];
    const float*  Wx3 = (const float*)d_in[5];
    const float*  Wy1 = (const float*)d_in[6];
    const float*  Wy2 = (const float*)d_in[7];
    const float*  Wy3 = (const float*)d_in[8];
    const float*  bx1 = (const float*)d_in[9];
    const float*  bx2 = (const float*)d_in[10];
    const float*  bx3 = (const float*)d_in[11];
    const float*  by1 = (const float*)d_in[12];
    const float*  by2 = (const float*)d_in[13];
    const float*  by3 = (const float*)d_in[14];
    const float*  W   = (const float*)d_in[15];
    float* out = (float*)d_out;

    int batch = in_sizes[0] / 2;   // x is [B,2]
    int block = 256;
    int grid  = (batch + block - 1) / block;
    tdb_cheb_kernel<<<grid, block, 0, stream>>>(x, y, Bm,
                                                Wx1, Wx2, Wx3, Wy1, Wy2, Wy3,
                                                bx1, bx2, bx3, by1, by2, by3,
                                                W, out, batch);
}